// Round 3
// baseline (242.257 us; speedup 1.0000x reference)
//
#include <hip/hip_runtime.h>
#include <stdint.h>

#define Mdim 4096
#define Kdim 4096
#define Ndim 4096

typedef __attribute__((ext_vector_type(4))) int v4i;
typedef __attribute__((ext_vector_type(16))) int v16i;

__device__ __forceinline__ void gload_lds16(const void* g, void* l) {
  __builtin_amdgcn_global_load_lds(
      (__attribute__((address_space(1))) void*)(uintptr_t)g,
      (__attribute__((address_space(3))) void*)(uint32_t)(uintptr_t)l,
      16, 0, 0);
}

// ---- pack x (int32 [M][K] -> int8 [M][K]) + row sums -----------------------
__global__ __launch_bounds__(256) void pack_x_kernel(const int* __restrict__ x,
                                                     char* __restrict__ x8,
                                                     int* __restrict__ rsx) {
  const int row = blockIdx.x;
  const int t = threadIdx.x;
  const int4* src = (const int4*)(x + (size_t)row * Kdim);
  int* dst = (int*)(x8 + (size_t)row * Kdim);
  int sum = 0;
#pragma unroll
  for (int i = 0; i < 4; ++i) {
    int4 v = src[t + 256 * i];
    sum += v.x + v.y + v.z + v.w;
    dst[t + 256 * i] =
        (v.x & 0xff) | ((v.y & 0xff) << 8) | ((v.z & 0xff) << 16) | (v.w << 24);
  }
#pragma unroll
  for (int o = 32; o > 0; o >>= 1) sum += __shfl_down(sum, o, 64);
  __shared__ int red[4];
  if ((t & 63) == 0) red[t >> 6] = sum;
  __syncthreads();
  if (t == 0) rsx[row] = red[0] + red[1] + red[2] + red[3];
}

// ---- pack + transpose y (int32 [K][N] -> int8 (y-128) [N][K]) + colsum -----
__global__ __launch_bounds__(256) void pack_yt_kernel(const int* __restrict__ y,
                                                      char* __restrict__ yt,
                                                      int* __restrict__ csy) {
  __shared__ int wt[64 * 17];
  const int t = threadIdx.x;
  const int n0 = blockIdx.x * 64;
  const int k0 = blockIdx.y * 64;
  const int c = t & 15;   // n-quad
  const int r0 = t >> 4;  // 0..15
#pragma unroll
  for (int s = 0; s < 4; ++s) {
    const int r = r0 + s * 16;  // k row 0..63
    int4 v = *(const int4*)(y + (size_t)(k0 + r) * Ndim + n0 + c * 4);
    v.x -= 128; v.y -= 128; v.z -= 128; v.w -= 128;
    wt[r * 17 + c] =
        (v.x & 0xff) | ((v.y & 0xff) << 8) | ((v.z & 0xff) << 16) | (v.w << 24);
  }
  __syncthreads();
  const int n = t >> 2;        // 0..63
  const int kq = t & 3;        // 16-k chunk
  const int colw = n >> 2;     // LDS word column
  const int byi = (n & 3) * 8; // byte select
  int outw[4];
  int bsum = 0;
#pragma unroll
  for (int j = 0; j < 4; ++j) {
    int b[4];
#pragma unroll
    for (int jj = 0; jj < 4; ++jj) {
      const int word = wt[(kq * 16 + j * 4 + jj) * 17 + colw];
      b[jj] = (word >> byi) & 0xff;
      bsum += (int)(char)b[jj];
    }
    outw[j] = b[0] | (b[1] << 8) | (b[2] << 16) | (b[3] << 24);
  }
  *(int4*)(yt + (size_t)(n0 + n) * Kdim + k0 + kq * 16) =
      make_int4(outw[0], outw[1], outw[2], outw[3]);
  bsum += __shfl_xor(bsum, 1, 64);
  bsum += __shfl_xor(bsum, 2, 64);
  if (kq == 0) atomicAdd(csy + n0 + n, bsum);
}

// ---- i8 GEMM: C = 7.5e-4*(A8 @ B8^T - 32*rsx[m] + 66*csy[n] - 2112*K) ------
// 512 thr / 8 waves, tile 256x256, BK=64, 1 block/CU.
// Register-double-banked, 1-tile read-ahead pipeline (4 LDS buffers, 128KB):
//   tile j: ds_read frags(j+1) -> reg bank (j+1)&1   (no consumer this tile!)
//           stage tile j+3 -> buf[(j+3)%4]           (4 x global_load_lds)
//           MFMA x16 on bank j&1 (frags loaded during tile j-1, lgkm drained
//           long ago) -> zero lgkm wait on the critical path; the 8-wave LDS
//           read burst (~770 cy incl. 4-way conflicts) hides under the MFMA
//           pipe drain (~1171 cy).
//           WAITV(4): the 4 newest vmem (this tile's staging) may fly; all
//           older staging certified -> next tile's frag reads safe. BAR.
// One barrier per K-tile (was 8). Safety chain: buf[(j+3)%4]'s readers ran
// during tile j-2 (ds_reads drained before tile j-1's MFMAs, certified by the
// barrier at end of j-1).
__global__ __launch_bounds__(512, 2) void gemm_i8_kernel(
    const char* __restrict__ A, const char* __restrict__ B,
    const int* __restrict__ rsx, const int* __restrict__ csy,
    float* __restrict__ out) {
  __shared__ __align__(16) char lds[4 * 32768];  // buf: [As 16K | Bs 16K] x4
  const int t = threadIdx.x;
  const int l = t & 63;
  const int w = t >> 6;      // 0..7
  const int warow = w >> 1;  // 0..3 (x64 rows)
  const int wbcol = w & 1;   // 0..1 (x128 cols)
  const int bm = blockIdx.y * 256;
  const int bn = blockIdx.x * 256;

  v16i acc[2][4];
#pragma unroll
  for (int i = 0; i < 2; ++i)
#pragma unroll
    for (int j = 0; j < 4; ++j)
#pragma unroll
      for (int q = 0; q < 16; ++q) acc[i][j][q] = 0;

  // Staging: thread t -> LDS row srow (+128), 16B slot (t&3); slot holds
  // global chunk (t&3)^((row>>1)&3); key (t>>3)&3 invariant under +128.
  const int srow = t >> 2;  // 0..127
  const int cswz = ((t & 3) ^ ((t >> 3) & 3)) * 16;
  const char* gA = A + (size_t)(bm + srow) * Kdim + cswz;
  const char* gB = B + (size_t)(bn + srow) * Kdim + cswz;

// Stage one full tile (4 x 16B-wide global_load_lds per wave).
#define STG4(buf_off, koff)                                                   \
  do {                                                                        \
    _Pragma("unroll") for (int i = 0; i < 2; ++i)                             \
        gload_lds16(gA + (koff) + (size_t)i * 128 * Kdim,                     \
                    lds + (buf_off) + i * 8192 + t * 16);                     \
    _Pragma("unroll") for (int i = 0; i < 2; ++i)                             \
        gload_lds16(gB + (koff) + (size_t)i * 128 * Kdim,                     \
                    lds + (buf_off) + 16384 + i * 8192 + t * 16);             \
  } while (0)

  const int arow = warow * 64 + (l & 31);
  const int brow = wbcol * 128 + (l & 31);
  const int lhalf = l >> 5;
  const int lkey = (l >> 1) & 3;  // == (frag_row>>1)&3 for all frag rows
  const int slot0 = ((0 + lhalf) ^ lkey) * 16;  // ks=0 16B slot
  const int slot1 = ((2 + lhalf) ^ lkey) * 16;  // ks=1 16B slot

  // Frag register banks: [bank][ks][frag]. 96 VGPRs total.
  v4i fa[2][2][2];
  v4i fb[2][2][4];

#define READF(BK, RBO)                                                        \
  do {                                                                        \
    const char* As_ = lds + (RBO);                                            \
    const char* Bs_ = lds + (RBO) + 16384;                                    \
    _Pragma("unroll") for (int i = 0; i < 2; ++i) {                           \
      fa[BK][0][i] = *(const v4i*)(As_ + (arow + i * 32) * 64 + slot0);       \
      fa[BK][1][i] = *(const v4i*)(As_ + (arow + i * 32) * 64 + slot1);       \
    }                                                                         \
    _Pragma("unroll") for (int j = 0; j < 4; ++j) {                           \
      fb[BK][0][j] = *(const v4i*)(Bs_ + (brow + j * 32) * 64 + slot0);       \
      fb[BK][1][j] = *(const v4i*)(Bs_ + (brow + j * 32) * 64 + slot1);       \
    }                                                                         \
  } while (0)

#define MFMA(a, b, c) __builtin_amdgcn_mfma_i32_32x32x32_i8(a, b, c, 0, 0, 0)
#define SETP(n) __builtin_amdgcn_s_setprio(n)
#define FENCE() __builtin_amdgcn_sched_barrier(0)
#define BAR()                                                                 \
  do {                                                                        \
    asm volatile("" ::: "memory");                                            \
    __builtin_amdgcn_s_barrier();                                             \
    asm volatile("" ::: "memory");                                            \
  } while (0)
#define WAITV(n) asm volatile("s_waitcnt vmcnt(" #n ")" ::: "memory")

#define DOMFMA(BK)                                                            \
  do {                                                                        \
    SETP(1);                                                                  \
    _Pragma("unroll") for (int ks = 0; ks < 2; ++ks)                          \
        _Pragma("unroll") for (int i = 0; i < 2; ++i)                         \
            _Pragma("unroll") for (int j = 0; j < 4; ++j)                     \
                acc[i][j] = MFMA(fa[BK][ks][i], fb[BK][ks][j], acc[i][j]);    \
    SETP(0);                                                                  \
  } while (0)

// Steady-state tile: read-ahead frags into RBK from RBO, stage SKOFF into
// SBO, MFMA on MBK, counted tail wait, single barrier.
#define TILEX(RBK, RBO, SBO, SKOFF, MBK)                                      \
  do {                                                                        \
    READF(RBK, RBO);                                                          \
    STG4(SBO, SKOFF);                                                         \
    FENCE();                                                                  \
    DOMFMA(MBK);                                                              \
    WAITV(4);                                                                 \
    BAR();                                                                    \
  } while (0)

  // Prologue: stage tiles 0,1,2 (12 loads in flight). Certify buf0 (WAITV(8))
  // -> read frags(0) into bank0. Certify buf1 (WAITV(4)) for tile 0's
  // read-ahead of frags(1); tile-2 staging stays in flight.
  STG4(0, 0);
  STG4(32768, 64);
  STG4(65536, 128);
  WAITV(8);
  BAR();
  READF(0, 0);
  WAITV(4);
  BAR();

  // Tiles 0..59: tile j reads buf[(j+1)%4], stages tile j+3 -> buf[(j+3)%4].
#pragma unroll 1
  for (int kt = 0; kt < 60; kt += 4) {
    TILEX(1, 32768, 98304, (kt + 3) * 64, 0);
    TILEX(0, 65536, 0, (kt + 4) * 64, 1);
    TILEX(1, 98304, 32768, (kt + 5) * 64, 0);
    TILEX(0, 0, 65536, (kt + 6) * 64, 1);
  }
  // j=60: read frags(61) <- buf1, stage tile 63 -> buf3, MFMA bank0.
  TILEX(1, 32768, 98304, 63 * 64, 0);
  // j=61: read frags(62) <- buf2, no stage; WAITV(0) certifies tile-63
  // staging before j=62 reads it.
  READF(0, 65536);
  FENCE();
  DOMFMA(1);
  WAITV(0);
  BAR();
  // j=62: read frags(63) <- buf3, no stage; nothing left to certify.
  READF(1, 98304);
  FENCE();
  DOMFMA(0);
  // j=63: pure compute on bank1.
  DOMFMA(1);

  // Epilogue. C/D 32x32 layout: col=lane&31, row=(r&3)+8*(r>>2)+4*(lane>>5)
  const int col = l & 31;
#pragma unroll
  for (int i = 0; i < 2; ++i) {
    const int gm0 = bm + warow * 64 + i * 32;
#pragma unroll
    for (int j = 0; j < 4; ++j) {
      const int gn = bn + wbcol * 128 + j * 32 + col;
      const int cs = 66 * csy[gn] - 8650752;  // -2112*4096
#pragma unroll
      for (int r = 0; r < 16; ++r) {
        const int row = (r & 3) + 8 * (r >> 2) + 4 * lhalf;
        const int gm = gm0 + row;
        const int val = acc[i][j][r] - 32 * rsx[gm] + cs;
        out[(size_t)gm * Ndim + gn] = 7.5e-4f * (float)val;
      }
    }
  }
#undef STG4
#undef READF
#undef TILEX
#undef DOMFMA
#undef MFMA
#undef SETP
#undef FENCE
#undef BAR
#undef WAITV
}

extern "C" void kernel_launch(void* const* d_in, const int* in_sizes, int n_in,
                              void* d_out, int out_size, void* d_ws, size_t ws_size,
                              hipStream_t stream) {
  (void)in_sizes; (void)n_in; (void)out_size; (void)ws_size;
  const int* x = (const int*)d_in[0];
  const int* y = (const int*)d_in[1];
  float* out = (float*)d_out;
  char* ws = (char*)d_ws;
  char* x8 = ws;                                          // 16 MB
  char* yt = ws + (size_t)Mdim * Kdim;                    // 16 MB
  int* rsx = (int*)(ws + (size_t)Mdim * Kdim + (size_t)Kdim * Ndim);
  int* csy = rsx + Mdim;

  hipMemsetAsync(csy, 0, Ndim * sizeof(int), stream);
  pack_x_kernel<<<Mdim, 256, 0, stream>>>(x, x8, rsx);
  pack_yt_kernel<<<dim3(Ndim / 64, Kdim / 64), 256, 0, stream>>>(y, yt, csy);
  gemm_i8_kernel<<<dim3(Ndim / 256, Mdim / 256), 512, 0, stream>>>(x8, yt, rsx, csy, out);
}